// Round 9
// baseline (469.628 us; speedup 1.0000x reference)
//
#include <hip/hip_runtime.h>
#include <hip/hip_bf16.h>

typedef __hip_bfloat16 bf16;
typedef __attribute__((ext_vector_type(8))) short short8;
typedef __attribute__((ext_vector_type(4))) float floatx4;
typedef __attribute__((address_space(3))) char c3;

template <int V> struct ic { static constexpr int value = V; };

__device__ __forceinline__ unsigned short f2bf(float x) {
  unsigned u = __builtin_bit_cast(unsigned, x);
  unsigned r = (u + 0x7fffu + ((u >> 16) & 1u)) >> 16;
  return (unsigned short)r;
}

#define GLL(g, l) __builtin_amdgcn_global_load_lds(                                  \
    (const __attribute__((address_space(1))) void*)(g),                              \
    (__attribute__((address_space(3))) void*)(l), 16, 0, 0)

template <int N> __device__ __forceinline__ void vmwait() {
  asm volatile("s_waitcnt vmcnt(%0)" ::"i"(N) : "memory");
}
template <int N> __device__ __forceinline__ void lgkwait() {
  asm volatile("s_waitcnt lgkmcnt(%0)" ::"i"(N) : "memory");
  __builtin_amdgcn_sched_barrier(0);
}
template <int OFF> __device__ __forceinline__ short8 dsr(unsigned a) {
  short8 r;
  asm volatile("ds_read_b128 %0, %1 offset:%2" : "=v"(r) : "v"(a), "i"(OFF));
  return r;
}
#define MFMA_(d, a, b) d = __builtin_amdgcn_mfma_f32_16x16x32_bf16(a, b, d, 0, 0, 0)

// ---------------- weight transpose+convert: fp32 [K][N] -> bf16 [N][K] ----------
__global__ __launch_bounds__(256) void wtrans_kernel(const float* __restrict__ in,
                                                     bf16* __restrict__ out,
                                                     int K, int N) {
  __shared__ float tile[32][33];
  int tx = threadIdx.x, ty = threadIdx.y;
  int n0 = blockIdx.x * 32, k0 = blockIdx.y * 32;
#pragma unroll
  for (int i = 0; i < 32; i += 8)
    tile[ty + i][tx] = in[(size_t)(k0 + ty + i) * N + (n0 + tx)];
  __syncthreads();
#pragma unroll
  for (int i = 0; i < 32; i += 8)
    out[(size_t)(n0 + ty + i) * K + (k0 + tx)] = __float2bfloat16(tile[tx][ty + i]);
}

// ---------------- LayerNorm fp32 -> bf16, D=1024, one block(256)/row ------------
__global__ __launch_bounds__(256) void ln_kernel(const float* __restrict__ x,
                                                 const float* __restrict__ g,
                                                 const float* __restrict__ b,
                                                 bf16* __restrict__ out) {
  const int D = 1024;
  size_t row = blockIdx.x;
  int t = threadIdx.x;
  float4 v = ((const float4*)(x + row * D))[t];
  float s  = v.x + v.y + v.z + v.w;
  float ss = v.x * v.x + v.y * v.y + v.z * v.z + v.w * v.w;
#pragma unroll
  for (int off = 32; off > 0; off >>= 1) {
    s  += __shfl_xor(s, off);
    ss += __shfl_xor(ss, off);
  }
  __shared__ float rs[4], rss[4];
  int wv = t >> 6;
  if ((t & 63) == 0) { rs[wv] = s; rss[wv] = ss; }
  __syncthreads();
  s  = rs[0] + rs[1] + rs[2] + rs[3];
  ss = rss[0] + rss[1] + rss[2] + rss[3];
  float mu  = s * (1.f / D);
  float inv = rsqrtf(ss * (1.f / D) - mu * mu + 1e-5f);
  float4 gv = ((const float4*)g)[t];
  float4 bv = ((const float4*)b)[t];
  ushort4 o;
  o.x = f2bf((v.x - mu) * inv * gv.x + bv.x);
  o.y = f2bf((v.y - mu) * inv * gv.y + bv.y);
  o.z = f2bf((v.z - mu) * inv * gv.z + bv.z);
  o.w = f2bf((v.w - mu) * inv * gv.w + bv.w);
  ((ushort4*)(out + row * D))[t] = o;
}

// ---------------- softmax: fp32 row (2048) -> bf16 written in place -------------
__global__ __launch_bounds__(256) void softmax_kernel(float* sc) {
  const int S = 2048;
  float* p = sc + (size_t)blockIdx.x * S;
  int t = threadIdx.x;
  float4 v0 = ((const float4*)p)[2 * t];
  float4 v1 = ((const float4*)p)[2 * t + 1];
  float f[8] = {v0.x, v0.y, v0.z, v0.w, v1.x, v1.y, v1.z, v1.w};
  float m = f[0];
#pragma unroll
  for (int j = 1; j < 8; ++j) m = fmaxf(m, f[j]);
#pragma unroll
  for (int off = 32; off > 0; off >>= 1) m = fmaxf(m, __shfl_xor(m, off));
  __shared__ float r1[4], r2[4];
  int wv = t >> 6;
  if ((t & 63) == 0) r1[wv] = m;
  __syncthreads();
  m = fmaxf(fmaxf(r1[0], r1[1]), fmaxf(r1[2], r1[3]));
  float s = 0.f;
#pragma unroll
  for (int j = 0; j < 8; ++j) { f[j] = __expf(f[j] - m); s += f[j]; }
#pragma unroll
  for (int off = 32; off > 0; off >>= 1) s += __shfl_xor(s, off);
  if ((t & 63) == 0) r2[wv] = s;
  __syncthreads();
  s = r2[0] + r2[1] + r2[2] + r2[3];
  float inv = 1.f / s;
  unsigned u0 = f2bf(f[0] * inv), u1 = f2bf(f[1] * inv);
  unsigned u2 = f2bf(f[2] * inv), u3 = f2bf(f[3] * inv);
  unsigned u4 = f2bf(f[4] * inv), u5 = f2bf(f[5] * inv);
  unsigned u6 = f2bf(f[6] * inv), u7 = f2bf(f[7] * inv);
  uint4 o;
  o.x = u0 | (u1 << 16);
  o.y = u2 | (u3 << 16);
  o.z = u4 | (u5 << 16);
  o.w = u6 | (u7 << 16);
  ((uint4*)p)[t] = o;
}

// ======= m201-geometry GEMM, BN=256 (gemm9w): BM=256,BN=256,BK=64, 8 waves ======
// Per-wave output 128x64 (acc[2][2][4][2] f32x4 = 128 regs). 4 phases/K-tile =
// C-quadrants, 16 MFMA each; reads {12,4,8,0}; ONE vmcnt(6) per K-tile; one
// half-tile (2xGLL) staged per phase. Staged "halves" grouped BY READ PHASE:
//   A-alpha = frag rows mi 0-3 of both wave-halves ({0-63}U{128-191}), read ph0
//   A-beta  = mi 4-7 rows, read ph2
//   B-gamma = n-frag 0-1 rows ({q*64+g*32..+32}), read ph0 (regs kept to ph3)
//   B-delta = n-frag 2-3 rows, read ph1
// Stage slots (all >=1 barrier after last reader): ph0: Abeta(kt+1);
// ph1: Aalpha(kt+2); ph2: Bgamma(kt+2); ph3: Bdelta(kt+2). FIFO: end-ph3 wait
// vmcnt(6) retires ALL of kt+1's halves, leaving 3 halves of kt+2 in flight.
// Tails: kt=nk-2 -> vmcnt(0); kt=nk-1 -> none. LDS 128KB, swizzle (row&7)<<4.
template <bool OUT_BF16, bool HAS_BIAS, bool HAS_RES, bool GELU, bool VTR>
__global__ __launch_bounds__(512, 2) void gemm9w(
    const bf16* __restrict__ A, int lda, size_t sA,
    const bf16* __restrict__ BT, int ldb, size_t sB,
    void* Cv, size_t sC,
    const float* __restrict__ bias, const float* res, bf16* vtr,
    int N, int K, float alpha, int gx, int gy) {
  __shared__ __align__(16) char ldsb[131072];
  const unsigned lds0 = (unsigned)(uintptr_t)(c3*)ldsb;

  const int tid = threadIdx.x;
  const int lane = tid & 63;
  const int wave = tid >> 6;
  const int wm = wave >> 2, wn = wave & 3;
  const int lr = lane & 15, lq = lane >> 4;

  int id = blockIdx.x;
  const int nwg = gridDim.x;
  if ((nwg & 7) == 0) id = (id & 7) * (nwg >> 3) + (id >> 3);  // XCD swizzle
  const int bx = id % gx;
  const int rem = id / gx;
  const int by = rem % gy;
  const int bz = rem / gy;
  const int m0 = by * 256, n0 = bx * 256;

  const int sidx = tid >> 3;  // 0..63
  const int schunk = ((tid & 7) ^ (sidx & 7)) * 8;  // pre-swizzled source chunk
  const bf16* gA = A + sA * bz + (size_t)(m0 + sidx) * lda + schunk;
  const int rowB = ((sidx >> 5) << 6) + (sidx & 31);  // {0-31, 64-95}
  const bf16* gB = BT + sB * bz + (size_t)(n0 + rowB) * ldb + schunk;

  const int nk = K >> 6;

  auto stA = [&](int tt, int h) {  // A half h: rows h*64+{0..63} and 128+h*64+{0..63}
    if (tt < nk) {
      const bf16* s = gA + (size_t)(h * 64) * lda + (size_t)tt * 64;
      char* d = ldsb + (((tt & 1) * 2 + h) << 14) + tid * 16;
      GLL(s, d);
      GLL(s + (size_t)128 * lda, d + 8192);
    }
  };
  auto stB = [&](int tt, int g) {  // B half g: rows q*64+g*32+{0..31}, q=0..3
    if (tt < nk) {
      const bf16* s = gB + (size_t)(g * 32) * ldb + (size_t)tt * 64;
      char* d = ldsb + 65536 + (((tt & 1) * 2 + g) << 14) + tid * 16;
      GLL(s, d);
      GLL(s + (size_t)128 * ldb, d + 8192);
    }
  };

  // read bases (within a 16KB half): idx*128 + swizzle; frag stride 2048; kh: ^64
  const unsigned aoff = (wm * 64 + lr) * 128 + ((lq ^ (lr & 7)) << 4);
  const unsigned boff = (wn * 32 + lr) * 128 + ((lq ^ (lr & 7)) << 4);

  floatx4 acc[2][2][4][2] = {};  // [mh][ng][mi][nl]

  // prologue: tile0 {Aa,Bg,Bd,Ab} + tile1 {Aa,Bg,Bd}; retire tile0 -> vmcnt(6)
  stA(0, 0); stB(0, 0); stB(0, 1); stA(0, 1);
  stA(1, 0); stB(1, 0); stB(1, 1);
  vmwait<6>();
  __builtin_amdgcn_s_barrier();

  auto body = [&](int kt, auto modeC) {
    constexpr int MODE = decltype(modeC)::value;  // 0 steady, 1 = nk-2, 2 = nk-1
    const unsigned p = (unsigned)(kt & 1);
    const unsigned Aa = lds0 + ((p * 2 + 0) << 14);
    const unsigned Ab = lds0 + ((p * 2 + 1) << 14);
    const unsigned Bg = lds0 + 65536 + ((p * 2 + 0) << 14);
    const unsigned Bd = lds0 + 65536 + ((p * 2 + 1) << 14);
    short8 a0[4], a1[4], g0[2], g1[2], d0[2], d1[2];

    // ---- ph0: read Aalpha(8) + Bgamma(4); stage Abeta(kt+1)
    {
      const unsigned aA = Aa + aoff, aX = aA ^ 64;
      a0[0] = dsr<0>(aA); a0[1] = dsr<2048>(aA); a0[2] = dsr<4096>(aA); a0[3] = dsr<6144>(aA);
      a1[0] = dsr<0>(aX); a1[1] = dsr<2048>(aX); a1[2] = dsr<4096>(aX); a1[3] = dsr<6144>(aX);
      const unsigned bA = Bg + boff, bX = bA ^ 64;
      g0[0] = dsr<0>(bA); g0[1] = dsr<2048>(bA);
      g1[0] = dsr<0>(bX); g1[1] = dsr<2048>(bX);
    }
    stA(kt + 1, 1);
    __builtin_amdgcn_s_barrier();
    lgkwait<0>();
    __builtin_amdgcn_s_setprio(1);
#pragma unroll
    for (int mi = 0; mi < 4; ++mi)
#pragma unroll
      for (int nl = 0; nl < 2; ++nl) MFMA_(acc[0][0][mi][nl], a0[mi], g0[nl]);
#pragma unroll
    for (int mi = 0; mi < 4; ++mi)
#pragma unroll
      for (int nl = 0; nl < 2; ++nl) MFMA_(acc[0][0][mi][nl], a1[mi], g1[nl]);
    __builtin_amdgcn_s_setprio(0);
    __builtin_amdgcn_s_barrier();

    // ---- ph1: read Bdelta(4); stage Aalpha(kt+2)
    {
      const unsigned bA = Bd + boff, bX = bA ^ 64;
      d0[0] = dsr<0>(bA); d0[1] = dsr<2048>(bA);
      d1[0] = dsr<0>(bX); d1[1] = dsr<2048>(bX);
    }
    stA(kt + 2, 0);
    __builtin_amdgcn_s_barrier();
    lgkwait<0>();
    __builtin_amdgcn_s_setprio(1);
#pragma unroll
    for (int mi = 0; mi < 4; ++mi)
#pragma unroll
      for (int nl = 0; nl < 2; ++nl) MFMA_(acc[0][1][mi][nl], a0[mi], d0[nl]);
#pragma unroll
    for (int mi = 0; mi < 4; ++mi)
#pragma unroll
      for (int nl = 0; nl < 2; ++nl) MFMA_(acc[0][1][mi][nl], a1[mi], d1[nl]);
    __builtin_amdgcn_s_setprio(0);
    __builtin_amdgcn_s_barrier();

    // ---- ph2: read Abeta(8) (overwrites a0/a1 - alpha dead); stage Bgamma(kt+2)
    {
      const unsigned aA = Ab + aoff, aX = aA ^ 64;
      a0[0] = dsr<0>(aA); a0[1] = dsr<2048>(aA); a0[2] = dsr<4096>(aA); a0[3] = dsr<6144>(aA);
      a1[0] = dsr<0>(aX); a1[1] = dsr<2048>(aX); a1[2] = dsr<4096>(aX); a1[3] = dsr<6144>(aX);
    }
    stB(kt + 2, 0);
    __builtin_amdgcn_s_barrier();
    lgkwait<0>();
    __builtin_amdgcn_s_setprio(1);
#pragma unroll
    for (int mi = 0; mi < 4; ++mi)
#pragma unroll
      for (int nl = 0; nl < 2; ++nl) MFMA_(acc[1][1][mi][nl], a0[mi], d0[nl]);
#pragma unroll
    for (int mi = 0; mi < 4; ++mi)
#pragma unroll
      for (int nl = 0; nl < 2; ++nl) MFMA_(acc[1][1][mi][nl], a1[mi], d1[nl]);
    __builtin_amdgcn_s_setprio(0);
    __builtin_amdgcn_s_barrier();

    // ---- ph3: no reads (g kept from ph0); stage Bdelta(kt+2); K-tile vmcnt
    stB(kt + 2, 1);
    __builtin_amdgcn_s_barrier();
    __builtin_amdgcn_s_setprio(1);
#pragma unroll
    for (int mi = 0; mi < 4; ++mi)
#pragma unroll
      for (int nl = 0; nl < 2; ++nl) MFMA_(acc[1][0][mi][nl], a0[mi], g0[nl]);
#pragma unroll
    for (int mi = 0; mi < 4; ++mi)
#pragma unroll
      for (int nl = 0; nl < 2; ++nl) MFMA_(acc[1][0][mi][nl], a1[mi], g1[nl]);
    __builtin_amdgcn_s_setprio(0);
    if constexpr (MODE == 0) vmwait<6>();
    else if constexpr (MODE == 1) vmwait<0>();
    __builtin_amdgcn_s_barrier();
  };

  for (int kt = 0; kt + 2 < nk; ++kt) body(kt, ic<0>{});
  body(nk - 2, ic<1>{});
  body(nk - 1, ic<2>{});

  // epilogue: C/D frag map col=lane&15, row=(lane>>4)*4+r [m89-verified]
  float* Cf = (float*)Cv;
  bf16* Cb = (bf16*)Cv;
  const size_t cb = sC * bz;
#pragma unroll
  for (int mh = 0; mh < 2; ++mh)
#pragma unroll
    for (int ng = 0; ng < 2; ++ng)
#pragma unroll
      for (int mi = 0; mi < 4; ++mi) {
        const int row = m0 + wm * 128 + (mh * 4 + mi) * 16 + lq * 4;
#pragma unroll
        for (int nl = 0; nl < 2; ++nl) {
          const int col = n0 + wn * 64 + (ng * 2 + nl) * 16 + lr;
          const float bb = HAS_BIAS ? bias[col] : 0.f;
#pragma unroll
          for (int r = 0; r < 4; ++r) {
            float val = acc[mh][ng][mi][nl][r] * alpha + bb;
            if (GELU) val = 0.5f * val * (1.f + erff(val * 0.70710678118654752f));
            if (HAS_RES) val += res[(size_t)(row + r) * N + col];
            const size_t idx = cb + (size_t)(row + r) * N + col;
            if (OUT_BF16) Cb[idx] = __float2bfloat16(val);
            else Cf[idx] = val;
            if (VTR) {
              if (col >= 2048) {  // V cols: also write V^T [b][col-2048][row%S]
                const int rr = row + r;
                vtr[(((size_t)(rr >> 11) << 10) + (col - 2048)) * 2048 + (rr & 2047)] =
                    __float2bfloat16(val);
              }
            }
          }
        }
      }
}

// ======= m201-geometry GEMM, BN=128 (gemm9n): 2 phases/K-tile of 16 MFMA =======
// Per-wave 128x32 (acc[2][4][2] = 64 regs). ph0: read Aalpha(8)+B(4), MFMA mh0;
// ph1: read Abeta(8), MFMA mh1 (B kept in regs). Stage: ph0: Abeta(kt+1);
// ph1: Aalpha(kt+2)+B(kt+2). ONE vmcnt(4)/K-tile (end-ph1 retires all of kt+1).
// LDS 96KB. Tails: nk-2 -> vmcnt(0); nk-1 -> none.
template <bool OUT_BF16, bool HAS_BIAS, bool HAS_RES, bool GELU, bool VTR>
__global__ __launch_bounds__(512, 2) void gemm9n(
    const bf16* __restrict__ A, int lda, size_t sA,
    const bf16* __restrict__ BT, int ldb, size_t sB,
    void* Cv, size_t sC,
    const float* __restrict__ bias, const float* res, bf16* vtr,
    int N, int K, float alpha, int gx, int gy) {
  __shared__ __align__(16) char ldsb[98304];
  const unsigned lds0 = (unsigned)(uintptr_t)(c3*)ldsb;

  const int tid = threadIdx.x;
  const int lane = tid & 63;
  const int wave = tid >> 6;
  const int wm = wave >> 2, wn = wave & 3;
  const int lr = lane & 15, lq = lane >> 4;

  int id = blockIdx.x;
  const int nwg = gridDim.x;
  if ((nwg & 7) == 0) id = (id & 7) * (nwg >> 3) + (id >> 3);
  const int bx = id % gx;
  const int rem = id / gx;
  const int by = rem % gy;
  const int bz = rem / gy;
  const int m0 = by * 256, n0 = bx * 128;

  const int sidx = tid >> 3;
  const int schunk = ((tid & 7) ^ (sidx & 7)) * 8;
  const bf16* gA = A + sA * bz + (size_t)(m0 + sidx) * lda + schunk;
  const bf16* gB = BT + sB * bz + (size_t)(n0 + sidx) * ldb + schunk;

  const int nk = K >> 6;

  auto stA = [&](int tt, int h) {
    if (tt < nk) {
      const bf16* s = gA + (size_t)(h * 64) * lda + (size_t)tt * 64;
      char* d = ldsb + (((tt & 1) * 2 + h) << 14) + tid * 16;
      GLL(s, d);
      GLL(s + (size_t)128 * lda, d + 8192);
    }
  };
  auto stBn = [&](int tt) {  // B tile 128 rows x 128B, linear
    if (tt < nk) {
      const bf16* s = gB + (size_t)tt * 64;
      char* d = ldsb + 65536 + ((tt & 1) << 14) + tid * 16;
      GLL(s, d);
      GLL(s + (size_t)64 * ldb, d + 8192);
    }
  };

  const unsigned aoff = (wm * 64 + lr) * 128 + ((lq ^ (lr & 7)) << 4);
  const unsigned boff = (wn * 32 + lr) * 128 + ((lq ^ (lr & 7)) << 4);

  floatx4 acc[2][4][2] = {};  // [mh][mi][nl]

  // prologue: tile0 {Aa,B,Ab} + tile1 {Aa,B}; retire tile0 -> vmcnt(4)
  stA(0, 0); stBn(0); stA(0, 1);
  stA(1, 0); stBn(1);
  vmwait<4>();
  __builtin_amdgcn_s_barrier();

  auto body = [&](int kt, auto modeC) {
    constexpr int MODE = decltype(modeC)::value;
    const unsigned p = (unsigned)(kt & 1);
    const unsigned Aa = lds0 + ((p * 2 + 0) << 14);
    const unsigned Ab = lds0 + ((p * 2 + 1) << 14);
    const unsigned Bb = lds0 + 65536 + (p << 14);
    short8 a0[4], a1[4], b0[2], b1[2];

    // ---- ph0: read Aalpha(8) + B(4); stage Abeta(kt+1); MFMA mh0
    {
      const unsigned aA = Aa + aoff, aX = aA ^ 64;
      a0[0] = dsr<0>(aA); a0[1] = dsr<2048>(aA); a0[2] = dsr<4096>(aA); a0[3] = dsr<6144>(aA);
      a1[0] = dsr<0>(aX); a1[1] = dsr<2048>(aX); a1[2] = dsr<4096>(aX); a1[3] = dsr<6144>(aX);
      const unsigned bA = Bb + boff, bX = bA ^ 64;
      b0[0] = dsr<0>(bA); b0[1] = dsr<2048>(bA);
      b1[0] = dsr<0>(bX); b1[1] = dsr<2048>(bX);
    }
    stA(kt + 1, 1);
    __builtin_amdgcn_s_barrier();
    lgkwait<0>();
    __builtin_amdgcn_s_setprio(1);
#pragma unroll
    for (int mi = 0; mi < 4; ++mi)
#pragma unroll
      for (int nl = 0; nl < 2; ++nl) MFMA_(acc[0][mi][nl], a0[mi], b0[nl]);
#pragma unroll
    for (int mi = 0; mi < 4; ++mi)
#pragma unroll
      for (int nl = 0; nl < 2; ++nl) MFMA_(acc[0][mi][nl], a1[mi], b1[nl]);
    __builtin_amdgcn_s_setprio(0);
    __builtin_amdgcn_s_barrier();

    // ---- ph1: read Abeta(8); stage Aalpha(kt+2)+B(kt+2); MFMA mh1; K-tile vmcnt
    {
      const unsigned aA = Ab + aoff, aX = aA ^ 64;
      a0[0] = dsr<0>(aA); a0[1] = dsr<2048>(aA); a0[2] = dsr<4096>(aA); a0[3] = dsr<6144>(aA);
      a1[0] = dsr<0>(aX); a1[1] = dsr<2048>(aX); a1[2] = dsr<4096>(aX); a1[3] = dsr<6144>(aX);
    }
    stA(kt + 2, 0); stBn(kt + 2);
    __builtin_amdgcn_s_barrier();
    lgkwait<0>();
    __builtin_amdgcn_s_setprio(1);
#pragma unroll
    for (int mi = 0; mi < 4; ++mi)
#pragma unroll
      for (int nl = 0; nl < 2; ++nl) MFMA_(acc[1][mi][nl], a0[mi], b0[nl]);
#pragma unroll
    for (int mi = 0; mi < 4; ++mi)
#pragma unroll
      for (int nl = 0; nl < 2; ++nl) MFMA_(acc[1][mi][nl], a1[mi], b1[nl]);
    __builtin_amdgcn_s_setprio(0);
    if constexpr (MODE == 0) vmwait<4>();
    else if constexpr (MODE == 1) vmwait<0>();
    __builtin_amdgcn_s_barrier();
  };

  for (int kt = 0; kt + 2 < nk; ++kt) body(kt, ic<0>{});
  body(nk - 2, ic<1>{});
  body(nk - 1, ic<2>{});

  // epilogue
  float* Cf = (float*)Cv;
  bf16* Cb = (bf16*)Cv;
  const size_t cb = sC * bz;
#pragma unroll
  for (int mh = 0; mh < 2; ++mh)
#pragma unroll
    for (int mi = 0; mi < 4; ++mi) {
      const int row = m0 + wm * 128 + (mh * 4 + mi) * 16 + lq * 4;
#pragma unroll
      for (int nl = 0; nl < 2; ++nl) {
        const int col = n0 + wn * 32 + nl * 16 + lr;
        const float bb = HAS_BIAS ? bias[col] : 0.f;
#pragma unroll
        for (int r = 0; r < 4; ++r) {
          float val = acc[mh][mi][nl][r] * alpha + bb;
          if (GELU) val = 0.5f * val * (1.f + erff(val * 0.70710678118654752f));
          if (HAS_RES) val += res[(size_t)(row + r) * N + col];
          const size_t idx = cb + (size_t)(row + r) * N + col;
          if (OUT_BF16) Cb[idx] = __float2bfloat16(val);
          else Cf[idx] = val;
          if (VTR) {
            if (col >= 2048) {
              const int rr = row + r;
              vtr[(((size_t)(rr >> 11) << 10) + (col - 2048)) * 2048 + (rr & 2047)] =
                  __float2bfloat16(val);
            }
          }
        }
      }
    }
}

extern "C" void kernel_launch(void* const* d_in, const int* in_sizes, int n_in,
                              void* d_out, int out_size, void* d_ws, size_t ws_size,
                              hipStream_t stream) {
  const int B = 4, S = 2048, D = 1024, DFF = 4096;
  const int M = B * S;
  const float* x   = (const float*)d_in[0];
  const float* wq  = (const float*)d_in[1];
  const float* bq  = (const float*)d_in[2];
  const float* wk  = (const float*)d_in[3];
  const float* bk  = (const float*)d_in[4];
  const float* wv  = (const float*)d_in[5];
  const float* bv  = (const float*)d_in[6];
  const float* wo  = (const float*)d_in[7];
  const float* bo  = (const float*)d_in[8];
  const float* w1  = (const float*)d_in[9];
  const float* b1  = (const float*)d_in[10];
  const float* w2  = (const float*)d_in[11];
  const float* b2  = (const float*)d_in[12];
  const float* g1  = (const float*)d_in[13];
  const float* be1 = (const float*)d_in[14];
  const float* g2  = (const float*)d_in[15];
  const float* be2 = (const float*)d_in[16];
  float* out = (float*)d_out;

  // workspace arena:
  //  0-6 wqkvT  6-8 woT  8-16 w1T  16-24 w2T  24 bqkv  25-41 h (bf16 MxD)
  //  41-89 qkv (bf16 Mx3072) / later hidden (bf16 MxDFF, 41-105)
  //  89-105 vT [4][D][S] bf16 (written by QKV epilogue)
  //  105+  scores fp32, chunk*16MB
  char* wsb = (char*)d_ws;
  const size_t MB1 = 1ull << 20;
  bf16* wqkvT = (bf16*)(wsb + 0 * MB1);
  bf16* woT   = (bf16*)(wsb + 6 * MB1);
  bf16* w1T   = (bf16*)(wsb + 8 * MB1);
  bf16* w2T   = (bf16*)(wsb + 16 * MB1);
  float* bqkv = (float*)(wsb + 24 * MB1);
  bf16* h     = (bf16*)(wsb + 25 * MB1);
  bf16* qkv   = (bf16*)(wsb + 41 * MB1);
  bf16* hidden = (bf16*)(wsb + 41 * MB1);
  bf16* vTall = (bf16*)(wsb + 89 * MB1);
  float* sc   = (float*)(wsb + 105 * MB1);

  int chunk = 1;
  if (ws_size > 105 * MB1) {
    size_t c = (ws_size - 105 * MB1) / (16 * MB1);
    chunk = (int)(c > 4 ? 4 : (c < 1 ? 1 : c));
  }

  dim3 tb(32, 8);
  wtrans_kernel<<<dim3(32, 32), tb, 0, stream>>>(wq, wqkvT, D, D);
  wtrans_kernel<<<dim3(32, 32), tb, 0, stream>>>(wk, wqkvT + (size_t)1024 * 1024, D, D);
  wtrans_kernel<<<dim3(32, 32), tb, 0, stream>>>(wv, wqkvT + (size_t)2048 * 1024, D, D);
  wtrans_kernel<<<dim3(32, 32), tb, 0, stream>>>(wo, woT, D, D);
  wtrans_kernel<<<dim3(128, 32), tb, 0, stream>>>(w1, w1T, D, DFF);
  wtrans_kernel<<<dim3(32, 128), tb, 0, stream>>>(w2, w2T, DFF, D);
  hipMemcpyAsync(bqkv, bq, 4096, hipMemcpyDeviceToDevice, stream);
  hipMemcpyAsync(bqkv + 1024, bk, 4096, hipMemcpyDeviceToDevice, stream);
  hipMemcpyAsync(bqkv + 2048, bv, 4096, hipMemcpyDeviceToDevice, stream);

  // h = LN1(x)
  ln_kernel<<<M, 256, 0, stream>>>(x, g1, be1, h);

  // qkv = h @ [wq|wk|wv] + biases; V cols also emitted transposed into vTall
  gemm9w<true, true, false, false, true><<<12 * 32, 512, 0, stream>>>(
      h, D, 0, wqkvT, D, 0, qkv, 0, bqkv, nullptr, vTall, 3072, D, 1.f, 12, 32);

  for (int b0 = 0; b0 < B; b0 += chunk) {
    int c = (B - b0 < chunk) ? (B - b0) : chunk;
    // scores = q @ k^T * 0.125 (fp32)
    gemm9w<false, false, false, false, false><<<64 * c, 512, 0, stream>>>(
        qkv + (size_t)b0 * S * 3072, 3072, (size_t)S * 3072,
        qkv + (size_t)b0 * S * 3072 + 1024, 3072, (size_t)S * 3072,
        sc, (size_t)S * S, nullptr, nullptr, nullptr, S, D, 0.125f, 8, 8);
    softmax_kernel<<<c * S, 256, 0, stream>>>(sc);
    // ctx = probs @ vT^T (probs bf16 in-place over fp32 rows, pitch 2S)
    gemm9n<true, false, false, false, false><<<64 * c, 512, 0, stream>>>(
        (const bf16*)sc, 2 * S, (size_t)S * 2 * S,
        vTall + (size_t)b0 * D * S, S, (size_t)D * S,
        h + (size_t)b0 * S * D, (size_t)S * D, nullptr, nullptr, nullptr, D, S, 1.f, 8, 8);
  }

  // x2 = ctx @ wo + bo + x -> d_out (fp32)
  gemm9n<false, true, true, false, false><<<8 * 32, 512, 0, stream>>>(
      h, D, 0, woT, D, 0, out, 0, bo, x, nullptr, D, D, 1.f, 8, 32);

  // h = LN2(x2)
  ln_kernel<<<M, 256, 0, stream>>>(out, g2, be2, h);

  // hidden = gelu(h @ w1 + b1)
  gemm9w<true, true, false, true, false><<<16 * 32, 512, 0, stream>>>(
      h, D, 0, w1T, D, 0, hidden, 0, b1, nullptr, nullptr, DFF, D, 1.f, 16, 32);

  // out = hidden @ w2 + b2 + x2 (in-place residual)
  gemm9n<false, true, true, false, false><<<8 * 32, 512, 0, stream>>>(
      hidden, DFF, 0, w2T, DFF, 0, out, 0, b2, out, nullptr, D, DFF, 1.f, 8, 32);
}